// Round 3
// baseline (2902.406 us; speedup 1.0000x reference)
//
#include <hip/hip_runtime.h>
#include <math.h>

constexpr int kB = 64, kN = 196, kENC = 2048, kDEC = 512, kE = 512, kATT = 512;
constexpr int kV = 32000, kT = 32, kTS = 31;
constexpr int kKIH = kE + kENC;        // 2560
constexpr int kKG  = kENC + kDEC;      // 2560 : per-step gates K = [ctx(2048); h(512)]
constexpr int kG   = 4 * kDEC;         // 2048
constexpr int kSPL = 8, kKSP = kKG / kSPL; // 320
constexpr int kM   = kTS * kB;         // 1984 rows (t*64+b)
constexpr int kMP  = 2048;             // padded

typedef __attribute__((ext_vector_type(8))) short bf8;
typedef __attribute__((ext_vector_type(4))) float f4;

__device__ __forceinline__ f4 mfma16(bf8 a, bf8 b, f4 c){
  asm("v_mfma_f32_16x16x32_bf16 %0, %1, %2, %0" : "+v"(c) : "v"(a), "v"(b));
  return c;
}
__device__ __forceinline__ float bf2f(unsigned short u){
  return __uint_as_float(((unsigned)u) << 16);
}
__device__ __forceinline__ unsigned short f2b(float f){
  unsigned u = __float_as_uint(f);
  u += 0x7fffu + ((u >> 16) & 1u);
  return (unsigned short)(u >> 16);
}
__device__ __forceinline__ float th_(float x){
  float e2 = __expf(2.f * x);
  return 1.f - 2.f * __builtin_amdgcn_rcpf(e2 + 1.f);
}
__device__ __forceinline__ float sg_(float x){
  return __builtin_amdgcn_rcpf(1.f + __expf(-x));
}

// ---------------- fp32 -> bf16 bulk convert ----------------
__global__ void k_cvt(const float* __restrict__ src, unsigned short* __restrict__ dst, int n8){
  int i = blockIdx.x * 256 + threadIdx.x;
  if (i >= n8) return;
  float4 a = ((const float4*)src)[2 * i];
  float4 b = ((const float4*)src)[2 * i + 1];
  union { unsigned short u[8]; uint4 v; } t;
  t.u[0] = f2b(a.x); t.u[1] = f2b(a.y); t.u[2] = f2b(a.z); t.u[3] = f2b(a.w);
  t.u[4] = f2b(b.x); t.u[5] = f2b(b.y); t.u[6] = f2b(b.z); t.u[7] = f2b(b.w);
  ((uint4*)dst)[i] = t.v;
}

// ---------------- fp32 [R][C] -> bf16 [C][R] ----------------
__global__ __launch_bounds__(256) void k_tcvt(const float* __restrict__ src,
                                              unsigned short* __restrict__ dst, int R, int C){
  __shared__ float t[32][33];
  int c0 = blockIdx.x * 32, r0 = blockIdx.y * 32;
  int tx = threadIdx.x & 31, ty = threadIdx.x >> 5;
  #pragma unroll
  for (int j = 0; j < 4; j++)
    t[ty + 8*j][tx] = src[(size_t)(r0 + ty + 8*j) * C + c0 + tx];
  __syncthreads();
  #pragma unroll
  for (int j = 0; j < 4; j++)
    dst[(size_t)(c0 + ty + 8*j) * R + r0 + tx] = f2b(t[tx][ty + 8*j]);
}

// ---------------- mean over N ----------------
__global__ void k_mean(const float* __restrict__ feat, float* __restrict__ meanf){
  int b = blockIdx.x, d = blockIdx.y * 256 + threadIdx.x;
  const float* p = feat + (size_t)b * kN * kENC + d;
  float s = 0.f;
  for (int n = 0; n < kN; n++) s += p[(size_t)n * kENC];
  meanf[b * kENC + d] = s * (1.f / kN);
}

// ---------------- h0 / c0 ----------------
__global__ __launch_bounds__(512) void k_init(const float* __restrict__ meanf,
                       const float* __restrict__ Wh, const float* __restrict__ bh,
                       const float* __restrict__ Wc, const float* __restrict__ bc,
                       float* __restrict__ h, float* __restrict__ c){
  __shared__ float mf[kENC];
  int b = blockIdx.x;
  for (int i = threadIdx.x; i < kENC; i += 512) mf[i] = meanf[b * kENC + i];
  __syncthreads();
  int j = threadIdx.x;
  const float* W  = blockIdx.y ? Wc : Wh;
  const float* bb = blockIdx.y ? bc : bh;
  float acc = bb[j];
  for (int k = 0; k < kENC; k++) acc = fmaf(mf[k], W[k * kDEC + j], acc);
  (blockIdx.y ? c : h)[b * kDEC + j] = acc;
}

// ---------------- gather embeddings: Xemb[t*64+b][512] ----------------
__global__ __launch_bounds__(512) void k_gather(const float* __restrict__ emb,
        const int* __restrict__ captions, unsigned short* __restrict__ Xemb){
  int m = blockIdx.x;            // 0..1983
  int t = m >> 6, b = m & 63, d = threadIdx.x;
  Xemb[(size_t)m * kE + d] = f2b(emb[(size_t)captions[b * kT + t] * kE + d]);
}

// ------- generic 16x64-per-wave MFMA GEMM: C_bf16[M][N] = A[M][K] @ Bt[N][K-slice]^T -------
// LDA = A row stride, LDB = B row stride, LDC = C row stride. K = reduction length.
template<int K, int LDA, int LDB, int LDC>
__global__ __launch_bounds__(256) void k_gemm_nt(const unsigned short* __restrict__ A,
                                                 const unsigned short* __restrict__ Bt,
                                                 unsigned short* __restrict__ Cb){
  int w = threadIdx.x >> 6, lane = threadIdx.x & 63;
  int m0 = blockIdx.x * 64 + w * 16, n0 = blockIdx.y * 64;
  int lr = lane & 15, lk = (lane >> 4) * 8;
  f4 acc[4] = {};
  const unsigned short* Ap = A  + (size_t)(m0 + lr) * LDA + lk;
  const unsigned short* Bp = Bt + (size_t)(n0 + lr) * LDB + lk;
  #pragma unroll 4
  for (int k0 = 0; k0 < K; k0 += 32){
    bf8 a  = *(const bf8*)(Ap + k0);
    bf8 b0 = *(const bf8*)(Bp + k0);
    bf8 b1 = *(const bf8*)(Bp + (size_t)16 * LDB + k0);
    bf8 b2 = *(const bf8*)(Bp + (size_t)32 * LDB + k0);
    bf8 b3 = *(const bf8*)(Bp + (size_t)48 * LDB + k0);
    acc[0] = mfma16(a, b0, acc[0]); acc[1] = mfma16(a, b1, acc[1]);
    acc[2] = mfma16(a, b2, acc[2]); acc[3] = mfma16(a, b3, acc[3]);
  }
  asm volatile("s_nop 7\n\ts_nop 7");
  int orow = (lane >> 4) * 4;
  #pragma unroll
  for (int nt = 0; nt < 4; nt++)
    #pragma unroll
    for (int r = 0; r < 4; r++)
      Cb[(size_t)(m0 + orow + r) * LDC + n0 + nt*16 + lr] = f2b(acc[nt][r]);
}

// ---------------- fused attention: e -> softmax -> context ----------------
__global__ __launch_bounds__(512) void k_att(const unsigned short* __restrict__ EA,
        const float* __restrict__ hWdec, const float* __restrict__ attv,
        const unsigned short* __restrict__ featb,
        unsigned short* __restrict__ Xb, float* __restrict__ alphas, int t){
  __shared__ float al[kN];
  int b = blockIdx.x, half = blockIdx.y;
  int tid = threadIdx.x, w = tid >> 6, lane = tid & 63;
  float hw[8], av[8];
  {
    const float* hp = hWdec + b * kATT + lane * 8;
    const float* ap = attv + lane * 8;
    #pragma unroll
    for (int j = 0; j < 8; j++){ hw[j] = hp[j]; av[j] = ap[j]; }
  }
  const unsigned short* eb = EA + (size_t)b * kN * kATT;
  for (int r = w; r < kN; r += 8){
    bf8 ev = *(const bf8*)(eb + (size_t)r * kATT + lane * 8);
    float s = 0.f;
    #pragma unroll
    for (int j = 0; j < 8; j++)
      s = fmaf(th_(bf2f((unsigned short)ev[j]) + hw[j]), av[j], s);
    #pragma unroll
    for (int off = 32; off; off >>= 1) s += __shfl_xor(s, off, 64);
    if (lane == 0) al[r] = s;
  }
  __syncthreads();
  if (w == 0){
    float v[4]; float mx = -1e30f;
    #pragma unroll
    for (int i = 0; i < 4; i++){
      int n = lane + 64 * i;
      v[i] = (n < kN) ? al[n] : -1e30f;
      mx = fmaxf(mx, v[i]);
    }
    #pragma unroll
    for (int off = 32; off; off >>= 1) mx = fmaxf(mx, __shfl_xor(mx, off, 64));
    float sum = 0.f;
    #pragma unroll
    for (int i = 0; i < 4; i++){ v[i] = __expf(v[i] - mx); sum += v[i]; }
    #pragma unroll
    for (int off = 32; off; off >>= 1) sum += __shfl_xor(sum, off, 64);
    float inv = 1.f / sum;
    #pragma unroll
    for (int i = 0; i < 4; i++){
      int n = lane + 64 * i;
      if (n < kN){
        float a = v[i] * inv;
        al[n] = a;
        if (half == 0) alphas[((size_t)b * kTS + t) * kN + n] = a;
      }
    }
  }
  __syncthreads();
  int d2 = half * 1024 + tid * 2;
  const unsigned short* fp = featb + (size_t)b * kN * kENC + d2;
  float c0 = 0.f, c1 = 0.f;
  #pragma unroll 4
  for (int n = 0; n < kN; n++){
    unsigned u = *(const unsigned*)(fp + (size_t)n * kENC);
    float a = al[n];
    c0 = fmaf(bf2f((unsigned short)(u & 0xffffu)), a, c0);
    c1 = fmaf(bf2f((unsigned short)(u >> 16)), a, c1);
  }
  *(unsigned*)(Xb + (size_t)b * kKG + d2) = ((unsigned)f2b(c1) << 16) | (unsigned)f2b(c0);
}

// ---------------- per-step gates GEMM split-K over K=2560 ----------------
__global__ __launch_bounds__(256) void k_gates(const unsigned short* __restrict__ X,
        const unsigned short* __restrict__ Wih, const unsigned short* __restrict__ Whh,
        float* __restrict__ gpart){
  int w = threadIdx.x >> 6, lane = threadIdx.x & 63;
  int n0 = blockIdx.x * 64 + w * 16, ks = blockIdx.y;
  int lr = lane & 15, lk = (lane >> 4) * 8;
  int nrow = n0 + lr;
  f4 acc[4] = {};
  const unsigned short* Xp = X + (size_t)lr * kKG + ks * kKSP + lk;
  #pragma unroll 2
  for (int kt = 0; kt < kKSP; kt += 32){
    int kk = ks * kKSP + kt + lk;
    bf8 a0 = *(const bf8*)(Xp + kt);
    bf8 a1 = *(const bf8*)(Xp + 16 * kKG + kt);
    bf8 a2 = *(const bf8*)(Xp + 32 * kKG + kt);
    bf8 a3 = *(const bf8*)(Xp + 48 * kKG + kt);
    const unsigned short* bp = (kk < kENC) ? (Wih + (size_t)nrow * kKIH + kE + kk)
                                           : (Whh + (size_t)nrow * kDEC + (kk - kENC));
    bf8 b = *(const bf8*)bp;
    acc[0] = mfma16(a0, b, acc[0]); acc[1] = mfma16(a1, b, acc[1]);
    acc[2] = mfma16(a2, b, acc[2]); acc[3] = mfma16(a3, b, acc[3]);
  }
  asm volatile("s_nop 7\n\ts_nop 7");
  float* gp = gpart + (size_t)ks * kB * kG;
  int orow = (lane >> 4) * 4;
  #pragma unroll
  for (int mt = 0; mt < 4; mt++)
    #pragma unroll
    for (int r = 0; r < 4; r++)
      gp[(size_t)(mt*16 + orow + r) * kG + n0 + lr] = acc[mt][r];
}

// ---------------- LSTM pointwise + h store + hWdec ----------------
__global__ __launch_bounds__(512) void k_lstm(const float* __restrict__ gpart,
      const unsigned short* __restrict__ Gxb,
      const float* __restrict__ bih, const float* __restrict__ bhh,
      float* __restrict__ c, unsigned short* __restrict__ Xb,
      unsigned short* __restrict__ Hall,
      const float* __restrict__ Wdec, float* __restrict__ hWdec, int t){
  __shared__ float hl[kDEC];
  int b = blockIdx.x, d = threadIdx.x;
  int m = t * kB + b;
  float gi = 0.f, gf = 0.f, gg = 0.f, go = 0.f;
  for (int ks = 0; ks < kSPL; ks++){
    const float* gp = gpart + ((size_t)ks * kB + b) * kG;
    gi += gp[d]; gf += gp[kDEC + d]; gg += gp[2*kDEC + d]; go += gp[3*kDEC + d];
  }
  const unsigned short* gx = Gxb + (size_t)m * kG;
  gi += bf2f(gx[d])          + bih[d]          + bhh[d];
  gf += bf2f(gx[kDEC + d])   + bih[kDEC + d]   + bhh[kDEC + d];
  gg += bf2f(gx[2*kDEC + d]) + bih[2*kDEC + d] + bhh[2*kDEC + d];
  go += bf2f(gx[3*kDEC + d]) + bih[3*kDEC + d] + bhh[3*kDEC + d];
  float cn = sg_(gf) * c[b*kDEC + d] + sg_(gi) * th_(gg);
  float hn = sg_(go) * th_(cn);
  c[b*kDEC + d] = cn;
  hl[d] = hn;
  unsigned short hb = f2b(hn);
  Xb[(size_t)b * kKG + kENC + d] = hb;
  Hall[(size_t)m * kDEC + d] = hb;
  __syncthreads();
  float a = 0.f;
  for (int k = 0; k < kDEC; k++) a = fmaf(hl[k], Wdec[(size_t)k * kATT + d], a);
  hWdec[b * kATT + d] = a;
}

// ---------------- initial h0 -> Xb + hWdec ----------------
__global__ __launch_bounds__(512) void k_prep(const float* __restrict__ h0,
      unsigned short* __restrict__ Xb,
      const float* __restrict__ Wdec, float* __restrict__ hWdec){
  __shared__ float hl[kDEC];
  int b = blockIdx.x, d = threadIdx.x;
  float hv = h0[b*kDEC + d];
  hl[d] = hv;
  Xb[(size_t)b * kKG + kENC + d] = f2b(hv);
  __syncthreads();
  float a = 0.f;
  for (int k = 0; k < kDEC; k++) a = fmaf(hl[k], Wdec[(size_t)k * kATT + d], a);
  hWdec[b * kATT + d] = a;
}

// ---------------- batched out-projection: [2048 x 512] @ outW ----------------
__global__ __launch_bounds__(256) void k_bigout(const unsigned short* __restrict__ Hall,
        const unsigned short* __restrict__ Wt,  // [32000][512]
        const float* __restrict__ bias, float* __restrict__ preds){
  int w = threadIdx.x >> 6, lane = threadIdx.x & 63;
  int m0 = blockIdx.x * 64 + w * 16, n0 = blockIdx.y * 128;
  int lr = lane & 15, lk = (lane >> 4) * 8;
  f4 acc[8];
  #pragma unroll
  for (int nt = 0; nt < 8; nt++){
    float bv = bias[n0 + nt*16 + lr];
    acc[nt] = (f4){bv, bv, bv, bv};
  }
  const unsigned short* Ap = Hall + (size_t)(m0 + lr) * kDEC + lk;
  const unsigned short* Bp = Wt + (size_t)(n0 + lr) * kDEC + lk;
  #pragma unroll 2
  for (int k0 = 0; k0 < kDEC; k0 += 32){
    bf8 a = *(const bf8*)(Ap + k0);
    #pragma unroll
    for (int nt = 0; nt < 8; nt++){
      bf8 b = *(const bf8*)(Bp + (size_t)nt * 16 * kDEC + k0);
      acc[nt] = mfma16(a, b, acc[nt]);
    }
  }
  asm volatile("s_nop 7\n\ts_nop 7");
  int orow = (lane >> 4) * 4;
  #pragma unroll
  for (int nt = 0; nt < 8; nt++)
    #pragma unroll
    for (int r = 0; r < 4; r++){
      int m = m0 + orow + r;
      if (m < kM){
        int t = m >> 6, b = m & 63;
        preds[((size_t)b * kTS + t) * kV + n0 + nt*16 + lr] = acc[nt][r];
      }
    }
}

extern "C" void kernel_launch(void* const* d_in, const int* in_sizes, int n_in,
                              void* d_out, int out_size, void* d_ws, size_t ws_size,
                              hipStream_t stream) {
  const float* feat     = (const float*)d_in[0];
  const int*   captions = (const int*)  d_in[1];
  const float* emb      = (const float*)d_in[2];
  const float* attWenc  = (const float*)d_in[3];
  const float* attWdec  = (const float*)d_in[4];
  const float* attv     = (const float*)d_in[5];
  const float* ihW      = (const float*)d_in[6];
  const float* ihb      = (const float*)d_in[7];
  const float* icW      = (const float*)d_in[8];
  const float* icb      = (const float*)d_in[9];
  const float* Wih      = (const float*)d_in[10];
  const float* Whh      = (const float*)d_in[11];
  const float* bih      = (const float*)d_in[12];
  const float* bhh      = (const float*)d_in[13];
  const float* outW     = (const float*)d_in[14];
  const float* outb     = (const float*)d_in[15];

  float* preds  = (float*)d_out;                       // [64][31][32000]
  float* alphas = preds + (size_t)kB * kTS * kV;       // [64][31][196]

  char* p = (char*)d_ws;
  unsigned short* featb  = (unsigned short*)p; p += (size_t)kB*kN*kENC*2;
  unsigned short* outWb  = (unsigned short*)p; p += (size_t)kV*kDEC*2;
  unsigned short* Wihb   = (unsigned short*)p; p += (size_t)kG*kKIH*2;
  unsigned short* Whhb   = (unsigned short*)p; p += (size_t)kG*kDEC*2;
  unsigned short* attWT  = (unsigned short*)p; p += (size_t)kATT*kENC*2;
  unsigned short* encattb= (unsigned short*)p; p += (size_t)kB*kN*kATT*2;
  unsigned short* Gxb    = (unsigned short*)p; p += (size_t)kMP*kG*2;
  unsigned short* Hall   = (unsigned short*)p; p += (size_t)kMP*kDEC*2;
  unsigned short* Xemb   = Hall;   // Xemb dead before first Hall write
  unsigned short* Xb     = (unsigned short*)p; p += (size_t)kB*kKG*2;
  float* gpart = (float*)p; p += (size_t)kSPL*kB*kG*4;
  float* meanf = (float*)p; p += (size_t)kB*kENC*4;
  float* h0    = (float*)p; p += (size_t)kB*kDEC*4;
  float* cbuf  = (float*)p; p += (size_t)kB*kDEC*4;
  float* hWdec = (float*)p; p += (size_t)kB*kATT*4;

  k_cvt<<<(kB*kN*kENC/8 + 255)/256, 256, 0, stream>>>(feat, featb, kB*kN*kENC/8);
  k_cvt<<<(kG*kKIH/8 + 255)/256, 256, 0, stream>>>(Wih, Wihb, kG*kKIH/8);
  k_cvt<<<(kG*kDEC/8 + 255)/256, 256, 0, stream>>>(Whh, Whhb, kG*kDEC/8);
  k_tcvt<<<dim3(kATT/32, kENC/32), 256, 0, stream>>>(attWenc, attWT, kENC, kATT);
  k_tcvt<<<dim3(kV/32, kDEC/32), 256, 0, stream>>>(outW, outWb, kDEC, kV);

  k_mean<<<dim3(kB, kENC/256), 256, 0, stream>>>(feat, meanf);
  k_init<<<dim3(kB, 2), 512, 0, stream>>>(meanf, ihW, ihb, icW, icb, h0, cbuf);

  // Gx[m][2048] = Xemb[m][512] @ Wih[:, 0:512]^T (bf16 out)
  k_gather<<<kM, 512, 0, stream>>>(emb, captions, Xemb);
  k_gemm_nt<kE, kE, kKIH, kG><<<dim3(kMP/64, kG/64), 256, 0, stream>>>(Xemb, Wihb, Gxb);

  // enc_att = featb @ attWT^T
  k_gemm_nt<kENC, kENC, kENC, kATT><<<dim3(kB*kN/64, kATT/64), 256, 0, stream>>>(featb, attWT, encattb);

  k_prep<<<kB, 512, 0, stream>>>(h0, Xb, attWdec, hWdec);

  for (int t = 0; t < kTS; ++t) {
    k_att<<<dim3(kB, 2), 512, 0, stream>>>(encattb, hWdec, attv, featb, Xb, alphas, t);
    k_gates<<<dim3(kG/64, kSPL), 256, 0, stream>>>(Xb, Wihb, Whhb, gpart);
    k_lstm<<<kB, 512, 0, stream>>>(gpart, Gxb, bih, bhh, cbuf, Xb, Hall,
                                   attWdec, hWdec, t);
  }

  k_bigout<<<dim3(kMP/64, kV/128), 256, 0, stream>>>(Hall, outWb, outb, preds);
}